// Round 1
// baseline (1467.516 us; speedup 1.0000x reference)
//
#include <hip/hip_runtime.h>
#include <hip/hip_bf16.h>

constexpr int Bc = 16, Nc = 400, Fc = 64, Tc = 12, NHc = 4, HDc = 16;
constexpr int NN = Nc * Nc;

// ---------------- CSR row pointers from sorted src ----------------
__global__ void k_rowptr(const int* __restrict__ src, int E, int* __restrict__ rowp) {
    for (int e = threadIdx.x; e < E; e += blockDim.x) {
        int s = src[e];
        if (e == 0 || src[e - 1] != s) rowp[s] = e;
    }
    if (threadIdx.x == 0) rowp[Nc] = E;
}

// ---------------- transpose wadj (per batch) ----------------
__global__ void k_transpose(const float* __restrict__ in, float* __restrict__ out) {
    __shared__ float tile[32][33];
    int b = blockIdx.z;
    int x0 = blockIdx.x * 32, y0 = blockIdx.y * 32;
    const float* inb = in + (size_t)b * NN;
    float* outb = out + (size_t)b * NN;
    for (int j = threadIdx.y; j < 32; j += 8) {
        int y = y0 + j, x = x0 + threadIdx.x;
        if (y < Nc && x < Nc) tile[j][threadIdx.x] = inb[y * Nc + x];
    }
    __syncthreads();
    for (int j = threadIdx.y; j < 32; j += 8) {
        int y = x0 + j, x = y0 + threadIdx.x;
        if (y < Nc && x < Nc) outb[y * Nc + x] = tile[threadIdx.x][j];
    }
}

// ---------------- wadj^2 at edge positions only ----------------
__global__ void k_w2e(const float* __restrict__ wadj, const float* __restrict__ wadjT,
                      const int* __restrict__ src, const int* __restrict__ dst,
                      int E, float* __restrict__ w2e) {
    int widx = (blockIdx.x * blockDim.x + threadIdx.x) >> 6;
    int lane = threadIdx.x & 63;
    if (widx >= Bc * E) return;
    int b = widx / E, e = widx % E;
    int i = src[e], j = dst[e];
    const float* ra = wadj + (size_t)b * NN + (size_t)i * Nc;
    const float* rb = wadjT + (size_t)b * NN + (size_t)j * Nc;
    float s = 0.f;
    for (int k = lane; k < Nc; k += 64) s += ra[k] * rb[k];
    for (int off = 32; off; off >>= 1) s += __shfl_xor(s, off, 64);
    if (lane == 0) w2e[widx] = s;
}

// ---------------- spatial QKV: (B,T,N,192) from x(B,N,F,T) ----------------
__global__ void k_qkv(const float* __restrict__ x,
                      const float* __restrict__ wq, const float* __restrict__ bq,
                      const float* __restrict__ wk, const float* __restrict__ bk,
                      const float* __restrict__ wv, const float* __restrict__ bv,
                      float* __restrict__ qkv) {
    long idx = (long)blockIdx.x * blockDim.x + threadIdx.x;
    int c = (int)(idx % 192);
    long row = idx / 192;               // (b*T+t)*N + n
    int n = (int)(row % Nc);
    int bt = (int)(row / Nc);
    int b = bt / Tc, t = bt % Tc;
    int sel = c >> 6, col = c & 63;
    const float* W = sel == 0 ? wq : sel == 1 ? wk : wv;
    const float* Bs = sel == 0 ? bq : sel == 1 ? bk : bv;
    const float* xp = x + (long)(b * Nc + n) * (Fc * Tc) + t;
    float acc = Bs[col];
#pragma unroll 8
    for (int f = 0; f < 64; ++f) acc += xp[f * 12] * W[f * 64 + col];
    qkv[idx] = acc;
}

// ---------------- spatial attention core: one block per (b,t,h) ----------------
__global__ __launch_bounds__(256) void k_sattn(const float* __restrict__ qkv,
                                               float* __restrict__ Os) {
    __shared__ float Kh[Nc * HDc];
    __shared__ float Vh[Nc * HDc];
    int bth = blockIdx.x;
    int h = bth % NHc;
    int bt = bth / NHc;
    const float* base = qkv + (long)bt * Nc * 192;
    for (int i = threadIdx.x; i < Nc * HDc; i += 256) {
        int n = i >> 4, d = i & 15;
        Kh[i] = base[n * 192 + 64 + h * 16 + d];
        Vh[i] = base[n * 192 + 128 + h * 16 + d];
    }
    __syncthreads();
    for (int nq = threadIdx.x; nq < Nc; nq += 256) {
        float q[16];
#pragma unroll
        for (int d = 0; d < 16; ++d) q[d] = base[nq * 192 + h * 16 + d];
        float m = -INFINITY, l = 0.f, acc[16];
#pragma unroll
        for (int d = 0; d < 16; ++d) acc[d] = 0.f;
        for (int k = 0; k < Nc; ++k) {
            float s = 0.f;
#pragma unroll
            for (int d = 0; d < 16; ++d) s += q[d] * Kh[k * 16 + d];
            s *= 0.25f;
            float mn = fmaxf(m, s);
            float corr = __expf(m - mn);
            float p = __expf(s - mn);
            l = l * corr + p;
#pragma unroll
            for (int d = 0; d < 16; ++d) acc[d] = acc[d] * corr + p * Vh[k * 16 + d];
            m = mn;
        }
        float inv = 1.f / l;
        float* op = Os + ((long)bt * Nc + nq) * 64 + h * 16;
#pragma unroll
        for (int d = 0; d < 16; ++d) op[d] = acc[d] * inv;
    }
}

// ---------------- generic row-64 projection: Y = X@W + b ----------------
__global__ void k_proj64(const float* __restrict__ X, const float* __restrict__ W,
                         const float* __restrict__ bias, float* __restrict__ Y, long rows) {
    long idx = (long)blockIdx.x * blockDim.x + threadIdx.x;
    if (idx >= rows * 64) return;
    int col = (int)(idx & 63);
    long row = idx >> 6;
    const float* xp = X + row * 64;
    float acc = bias[col];
#pragma unroll 8
    for (int g = 0; g < 64; ++g) acc += xp[g] * W[g * 64 + col];
    Y[idx] = acc;
}

// ---------------- temporal MHA fused per (b,n); ta stored (B,N,F,T) ----------------
__global__ __launch_bounds__(256) void k_tattn(const float* __restrict__ x,
    const float* __restrict__ wq, const float* __restrict__ bq,
    const float* __restrict__ wk, const float* __restrict__ bk,
    const float* __restrict__ wv, const float* __restrict__ bv,
    const float* __restrict__ wo, const float* __restrict__ bo,
    float* __restrict__ ta) {
    __shared__ float xl[Fc * Tc];        // [f*12+t]
    __shared__ float qkvl[Tc * 192];
    __shared__ float ol[Tc * 65];
    int bn = blockIdx.x;
    const float* xrow = x + (long)bn * (Fc * Tc);
    for (int i = threadIdx.x; i < Fc * Tc; i += 256) xl[i] = xrow[i];
    __syncthreads();
    for (int i = threadIdx.x; i < Tc * 192; i += 256) {
        int t = i / 192, c = i % 192;
        int sel = c >> 6, col = c & 63;
        const float* W = sel == 0 ? wq : sel == 1 ? wk : wv;
        const float* Bs = sel == 0 ? bq : sel == 1 ? bk : bv;
        float acc = Bs[col];
#pragma unroll 8
        for (int f = 0; f < 64; ++f) acc += xl[f * 12 + t] * W[f * 64 + col];
        qkvl[i] = acc;
    }
    __syncthreads();
    for (int i = threadIdx.x; i < Tc * 64; i += 256) {
        int t = i >> 6, rem = i & 63;
        int h = rem >> 4, d = rem & 15;
        float s[12];
        float mx = -INFINITY;
        for (int k = 0; k < 12; ++k) {
            float acc = 0.f;
#pragma unroll
            for (int dd = 0; dd < 16; ++dd)
                acc += qkvl[t * 192 + h * 16 + dd] * qkvl[k * 192 + 64 + h * 16 + dd];
            s[k] = acc * 0.25f;
            mx = fmaxf(mx, s[k]);
        }
        float l = 0.f;
        for (int k = 0; k < 12; ++k) { s[k] = __expf(s[k] - mx); l += s[k]; }
        float inv = 1.f / l, o = 0.f;
        for (int k = 0; k < 12; ++k) o += s[k] * qkvl[k * 192 + 128 + h * 16 + d];
        ol[t * 65 + rem] = o * inv;
    }
    __syncthreads();
    float* orow = ta + (long)bn * (Fc * Tc);
    for (int i = threadIdx.x; i < Fc * Tc; i += 256) {
        int fo = i / 12, t = i % 12;
        float acc = bo[fo];
#pragma unroll 8
        for (int g = 0; g < 64; ++g) acc += ol[t * 65 + g] * wo[g * 64 + fo];
        orow[i] = acc;   // i == fo*12 + t
    }
}

// ---------------- sparse agg_conv: Y = sigmoid(f1@W1 + f2@W2), X in (B,T,N,64) ----------------
__global__ __launch_bounds__(256) void k_agg(const float* __restrict__ X,
    const float* __restrict__ wadj, const float* __restrict__ w2e,
    const int* __restrict__ rowp, const int* __restrict__ dst,
    const float* __restrict__ thA, const float* __restrict__ thB,
    const float* __restrict__ W1, const float* __restrict__ W2,
    int E, float* __restrict__ Y) {
    __shared__ float f1l[32 * 64];
    __shared__ float f2l[32 * 64];
    int blk = blockIdx.x;
    int rchunk = blk % 13;
    int bt = blk / 13;
    int b = bt / Tc;
    int r0 = rchunk * 32;
    const float* Xbt = X + (long)bt * Nc * 64;
    const float* wrow = wadj + (size_t)b * NN;
    const float* w2b = w2e + (size_t)b * E;
    for (int idx = threadIdx.x; idx < 32 * 64; idx += 256) {
        int rl = idx >> 6, f = idx & 63;
        int i = r0 + rl;
        float a1 = 0.f, a2 = 0.f;
        if (i < Nc) {
            int e0 = rowp[i], e1 = rowp[i + 1];
            float invnc = 1.f / ((float)(e1 - e0 - 1) + 1e-10f);
            float tA = thA[i], tB = thB[i];
            for (int e = e0; e < e1; ++e) {
                int j = dst[e];
                float sc = (j == i) ? 1.f : invnc;
                float xv = Xbt[j * 64 + f];
                a1 += wrow[i * Nc + j] * (tA * sc) * xv;
                a2 += w2b[e] * (tB * sc) * xv;
            }
        }
        f1l[idx] = a1;
        f2l[idx] = a2;
    }
    __syncthreads();
    for (int idx = threadIdx.x; idx < 32 * 64; idx += 256) {
        int rl = idx >> 6, fo = idx & 63;
        int i = r0 + rl;
        if (i >= Nc) continue;
        float acc = 0.f;
#pragma unroll 8
        for (int g = 0; g < 64; ++g)
            acc += f1l[rl * 64 + g] * W1[g * 64 + fo] + f2l[rl * 64 + g] * W2[g * 64 + fo];
        Y[((long)bt * Nc + i) * 64 + fo] = 1.f / (1.f + __expf(-acc));
    }
}

// ---------------- neighborhood max (incl self) ----------------
__global__ void k_segmax(const float* __restrict__ h, const int* __restrict__ rowp,
                         const int* __restrict__ dst, float* __restrict__ Y) {
    long idx = (long)blockIdx.x * blockDim.x + threadIdx.x;
    if (idx >= (long)Bc * Tc * Nc * 64) return;
    int f = (int)(idx & 63);
    long rn = idx >> 6;
    int n = (int)(rn % Nc);
    long bt = rn / Nc;
    int e0 = rowp[n], e1 = rowp[n + 1];
    float m = -INFINITY;
    const float* hb = h + bt * Nc * 64;
    for (int e = e0; e < e1; ++e) m = fmaxf(m, hb[dst[e] * 64 + f]);
    Y[idx] = m;
}

// ---------------- gated temporal conv; 4 (b,n) per block, lane = out-channel ----------------
__global__ __launch_bounds__(256) void k_gated(const float* __restrict__ ta,
    const float* __restrict__ tcw, const float* __restrict__ tcb,
    const float* __restrict__ gcw, const float* __restrict__ gcb,
    float* __restrict__ gated) {
    __shared__ float wl[64 * 192];       // [(ic*3+dt)*64 + o]
    __shared__ float tal[4][768];
    int wave = threadIdx.x >> 6, lane = threadIdx.x & 63;
    int bn = blockIdx.x * 4 + wave;
    for (int idx = threadIdx.x; idx < 64 * 192; idx += 256) {
        int o = idx / 192, r = idx % 192;
        wl[r * 64 + o] = tcw[idx];
    }
    {
        const float* tr = ta + (long)bn * 768;
        for (int i = lane; i < 768; i += 64) tal[wave][i] = tr[i];
    }
    __syncthreads();
    int o = lane;
    float acc_t[12], acc_g[12];
#pragma unroll
    for (int t = 0; t < 12; ++t) acc_t[t] = tcb[o];
    for (int ic = 0; ic < 64; ++ic) {
        float xe[14];
        xe[0] = 0.f; xe[13] = 0.f;
#pragma unroll
        for (int t = 0; t < 12; ++t) xe[t + 1] = tal[wave][ic * 12 + t];
        float w0 = wl[(ic * 3 + 0) * 64 + o];
        float w1 = wl[(ic * 3 + 1) * 64 + o];
        float w2 = wl[(ic * 3 + 2) * 64 + o];
#pragma unroll
        for (int t = 0; t < 12; ++t)
            acc_t[t] += xe[t] * w0 + xe[t + 1] * w1 + xe[t + 2] * w2;
    }
    __syncthreads();
    for (int idx = threadIdx.x; idx < 64 * 192; idx += 256) {
        int o2 = idx / 192, r = idx % 192;
        wl[r * 64 + o2] = gcw[idx];
    }
    __syncthreads();
#pragma unroll
    for (int t = 0; t < 12; ++t) acc_g[t] = gcb[o];
    for (int ic = 0; ic < 64; ++ic) {
        float xe[14];
        xe[0] = 0.f; xe[13] = 0.f;
#pragma unroll
        for (int t = 0; t < 12; ++t) xe[t + 1] = tal[wave][ic * 12 + t];
        float w0 = wl[(ic * 3 + 0) * 64 + o];
        float w1 = wl[(ic * 3 + 1) * 64 + o];
        float w2 = wl[(ic * 3 + 2) * 64 + o];
#pragma unroll
        for (int t = 0; t < 12; ++t)
            acc_g[t] += xe[t] * w0 + xe[t + 1] * w1 + xe[t + 2] * w2;
    }
    int b = bn / Nc, n = bn % Nc;
#pragma unroll
    for (int t = 0; t < 12; ++t) {
        float g = acc_t[t] * (1.f / (1.f + __expf(-acc_g[t])));
        gated[((long)(b * Tc + t) * Nc + n) * 64 + o] = g;
    }
}

// ---------------- final: mask + gated + residual relu + layernorm ----------------
__global__ __launch_bounds__(256) void k_final(const float* __restrict__ mean2,
    const float* __restrict__ gated, const float* __restrict__ x,
    const float* __restrict__ mw, const float* __restrict__ md,
    const float* __restrict__ lng, const float* __restrict__ lnb,
    const int* __restrict__ maskp, float* __restrict__ out) {
    __shared__ float xl[64 * 13];
    __shared__ float rl[64 * 13];
    int bn = blockIdx.x;
    int b = bn / Nc, n = bn % Nc;
    const float* xrow = x + (long)bn * 768;
    for (int i = threadIdx.x; i < 768; i += 256)
        xl[(i / 12) * 13 + (i % 12)] = xrow[i];
    __syncthreads();
    float maskf = maskp[0] ? (mw[bn] * md[bn]) : 1.f;
    int wave = threadIdx.x >> 6, f = threadIdx.x & 63;
    for (int t = wave; t < 12; t += 4) {
        long base = ((long)(b * Tc + t) * Nc + n) * 64;
        float v = mean2[base + f] * maskf + gated[base + f];
        float r = v + xl[f * 13 + t];
        r = fmaxf(r, 0.f);
        float s = r;
        for (int off = 32; off; off >>= 1) s += __shfl_xor(s, off, 64);
        float mu = s * (1.f / 64.f);
        float d = r - mu;
        float vs = d * d;
        for (int off = 32; off; off >>= 1) vs += __shfl_xor(vs, off, 64);
        float var = vs * (1.f / 64.f);
        float y = d * rsqrtf(var + 1e-5f) * lng[f] + lnb[f];
        rl[f * 13 + t] = y;
    }
    __syncthreads();
    float* orow = out + (long)bn * 768;
    for (int i = threadIdx.x; i < 768; i += 256)
        orow[i] = rl[(i / 12) * 13 + (i % 12)];
}

extern "C" void kernel_launch(void* const* d_in, const int* in_sizes, int n_in,
                              void* d_out, int out_size, void* d_ws, size_t ws_size,
                              hipStream_t stream) {
    const float* x    = (const float*)d_in[0];
    const float* wadj = (const float*)d_in[1];
    const float* mw   = (const float*)d_in[2];
    const float* md   = (const float*)d_in[3];
    const float* th1  = (const float*)d_in[4];
    const float* th2  = (const float*)d_in[5];
    const float* th3  = (const float*)d_in[6];
    const float* th4  = (const float*)d_in[7];
    const float* gw1a = (const float*)d_in[8];
    const float* gw1b = (const float*)d_in[9];
    const float* gw2a = (const float*)d_in[10];
    const float* gw2b = (const float*)d_in[11];
    const float* mpw  = (const float*)d_in[12];
    const float* mpb  = (const float*)d_in[13];
    const float* tcw  = (const float*)d_in[14];
    const float* tcb  = (const float*)d_in[15];
    const float* gcw  = (const float*)d_in[16];
    const float* gcb  = (const float*)d_in[17];
    const float* sqw  = (const float*)d_in[18]; const float* sqb = (const float*)d_in[19];
    const float* skw  = (const float*)d_in[20]; const float* skb = (const float*)d_in[21];
    const float* svw  = (const float*)d_in[22]; const float* svb = (const float*)d_in[23];
    const float* sow  = (const float*)d_in[24]; const float* sob = (const float*)d_in[25];
    const float* tqw  = (const float*)d_in[26]; const float* tqb = (const float*)d_in[27];
    const float* tkw  = (const float*)d_in[28]; const float* tkb = (const float*)d_in[29];
    const float* tvw  = (const float*)d_in[30]; const float* tvb = (const float*)d_in[31];
    const float* tow  = (const float*)d_in[32]; const float* tob = (const float*)d_in[33];
    const float* lng  = (const float*)d_in[34]; const float* lnb = (const float*)d_in[35];
    const int* eidx   = (const int*)d_in[37];
    const int* maskp  = (const int*)d_in[38];
    int E = in_sizes[37] / 2;
    const int* esrc = eidx;
    const int* edst = eidx + E;

    const long SZ_BTNF = (long)Bc * Tc * Nc * 64;        // 4,915,200
    float* ws = (float*)d_ws;
    float* qkv   = ws;                                   // 3*SZ_BTNF, reused below
    float* mean1 = ws;                                   // reuse of qkv[0:SZ)
    float* gatedb = ws;                                  // reuse after mean1 dead
    float* hbuf  = ws + SZ_BTNF;                         // reuse of qkv[SZ:2SZ)
    float* maxp  = ws + 2 * SZ_BTNF;                     // reuse of qkv[2SZ:3SZ)
    float* Os    = ws + 3 * SZ_BTNF;                     // SZ; reused as mean2
    float* mean2 = Os;
    float* sa    = Os + SZ_BTNF;                         // SZ
    float* ta    = sa + SZ_BTNF;                         // SZ
    float* wadjT = ta + SZ_BTNF;                         // B*N*N
    float* w2e   = wadjT + (long)Bc * NN;                // B*E
    int*   rowp  = (int*)(w2e + (long)Bc * E);           // N+1

    hipLaunchKernelGGL(k_rowptr, dim3(1), dim3(256), 0, stream, esrc, E, rowp);
    hipLaunchKernelGGL(k_transpose, dim3(13, 13, Bc), dim3(32, 8), 0, stream, wadj, wadjT);
    int w2blocks = (Bc * E + 3) / 4;
    hipLaunchKernelGGL(k_w2e, dim3(w2blocks), dim3(256), 0, stream, wadj, wadjT, esrc, edst, E, w2e);
    hipLaunchKernelGGL(k_qkv, dim3(57600), dim3(256), 0, stream, x, sqw, sqb, skw, skb, svw, svb, qkv);
    hipLaunchKernelGGL(k_sattn, dim3(768), dim3(256), 0, stream, qkv, Os);
    hipLaunchKernelGGL(k_proj64, dim3(19200), dim3(256), 0, stream, Os, sow, sob, sa, (long)(Bc * Tc * Nc));
    hipLaunchKernelGGL(k_tattn, dim3(6400), dim3(256), 0, stream, x, tqw, tqb, tkw, tkb, tvw, tvb, tow, tob, ta);
    hipLaunchKernelGGL(k_agg, dim3(2496), dim3(256), 0, stream, sa, wadj, w2e, rowp, edst, th1, th2, gw1a, gw1b, E, mean1);
    hipLaunchKernelGGL(k_proj64, dim3(19200), dim3(256), 0, stream, mean1, mpw, mpb, hbuf, (long)(Bc * Tc * Nc));
    hipLaunchKernelGGL(k_segmax, dim3(19200), dim3(256), 0, stream, hbuf, rowp, edst, maxp);
    hipLaunchKernelGGL(k_agg, dim3(2496), dim3(256), 0, stream, maxp, wadj, w2e, rowp, edst, th3, th4, gw2a, gw2b, E, mean2);
    hipLaunchKernelGGL(k_gated, dim3(1600), dim3(256), 0, stream, ta, tcw, tcb, gcw, gcb, gatedb);
    hipLaunchKernelGGL(k_final, dim3(6400), dim3(256), 0, stream, mean2, gatedb, x, mw, md, lng, lnb, maskp, (float*)d_out);
}